// Round 4
// baseline (567.273 us; speedup 1.0000x reference)
//
#include <hip/hip_runtime.h>
#include <hip/hip_bf16.h>

// Problem constants (fixed by reference)
#define NN 100000
#define EE 1600000
#define HH 128
#define NB 391      // buckets = ceil(NN/256)
#define CAP 5120    // padded bucket capacity (mean 4096, sigma 64 -> +16 sigma)
#define GB 1563     // gemm blocks = ceil(NN/64)
#define SB 64       // scatter blocks (r19: was 391 — 153K atomics to 391 addrs
                    // serialized ~390-deep chains = the invariant ~70us critical
                    // path of gemm0_scatter; 64 blocks -> 64-deep chains)
#define EPB (EE / SB)   // 25000 edges per scatter block (exact)

typedef short bf16x8 __attribute__((ext_vector_type(8)));
typedef short bf16x4 __attribute__((ext_vector_type(4)));
typedef float f32x4  __attribute__((ext_vector_type(4)));

__device__ inline short f2bf(float v) {
    __hip_bfloat16 b = __float2bfloat16(v);
    return *reinterpret_cast<short*>(&b);
}

// direct global->LDS staging (16B per lane, LDS dest = uniform base + lane*16)
typedef __attribute__((address_space(1))) void gvoid_t;
typedef __attribute__((address_space(3))) void svoid_t;
__device__ __forceinline__ void gload16(const void* g, void* l) {
    __builtin_amdgcn_global_load_lds((gvoid_t*)g, (svoid_t*)l, 16, 0, 0);
}

// Compiler-order fence: pins the ISSUE ORDER of vmem groups so the counted
// vmcnt arithmetic below is valid (r2 lesson: inline-asm waitcnt orders the
// HW, not the compiler).
__device__ __forceinline__ void ld_fence() { asm volatile("" ::: "memory"); }

// counted-vmcnt barrier: wait own outstanding vmem down to N, then raw
// s_barrier. N derived from the fenced issue order in gemm_body.
template <int N>
__device__ __forceinline__ void wait_vm_bar() {
    if constexpr (N == 0)
        asm volatile("s_waitcnt vmcnt(0)\n\ts_barrier" ::: "memory");
    else if constexpr (N == 8)
        asm volatile("s_waitcnt vmcnt(8)\n\ts_barrier" ::: "memory");
    else if constexpr (N == 12)
        asm volatile("s_waitcnt vmcnt(12)\n\ts_barrier" ::: "memory");
    else if constexpr (N == 16)
        asm volatile("s_waitcnt vmcnt(16)\n\ts_barrier" ::: "memory");
    else if constexpr (N == 18)
        asm volatile("s_waitcnt vmcnt(18)\n\ts_barrier" ::: "memory");
    else if constexpr (N == 20)
        asm volatile("s_waitcnt vmcnt(20)\n\ts_barrier" ::: "memory");
    else
        static_assert(N == 0 || N == 8 || N == 12 || N == 16 || N == 18 || N == 20,
                      "bad N");
}
__device__ __forceinline__ void barrier_only() {
    asm volatile("s_barrier" ::: "memory");
}

// ---------------------------------------------------------------------------
// Launch 1: weight prep (blocks 0..127) + zero bucket cursors (block 128)
// ---------------------------------------------------------------------------
__global__ __launch_bounds__(1024) void prep_kernel(
    const float* __restrict__ Wl0, const float* __restrict__ Wr0,
    const float* __restrict__ Wl1, const float* __restrict__ Wr1,
    const float* __restrict__ Wl2, const float* __restrict__ Wr2,
    __hip_bfloat16* __restrict__ WT0, __hip_bfloat16* __restrict__ WT1,
    __hip_bfloat16* __restrict__ WT2, int* __restrict__ bcur) {
    const int t = threadIdx.x;
    if (blockIdx.x == 128) {
        if (t < NB) bcur[t] = 0;
        return;
    }
    int id = blockIdx.x * 1024 + t;              // 0 .. 131071
    if (id < 65536) {                            // layer 0: K=256
        int k = id & 255, n = id >> 8;
        float v = (n < 128) ? Wl0[(size_t)k * 128 + n]
                            : Wr0[(size_t)k * 128 + (n - 128)];
        WT0[(size_t)n * 256 + k] = __float2bfloat16(v);
    } else {
        id -= 65536;
        int layer = id >> 15;                    // 0 -> L1, 1 -> L2
        int u = id & 32767;
        int k = u & 127, n = u >> 7;
        const float* Wl = layer ? Wl2 : Wl1;
        const float* Wr = layer ? Wr2 : Wr1;
        __hip_bfloat16* WT = layer ? WT2 : WT1;
        float v = (n < 128) ? Wl[(size_t)k * 128 + n]
                            : Wr[(size_t)k * 128 + (n - 128)];
        WT[(size_t)n * 128 + k] = __float2bfloat16(v);
    }
}

// ---------------------------------------------------------------------------
// MFMA GEMM body (r18, unchanged): [z | r] = h @ [Wl|Wr], 64-row tile, 4 waves.
// Weights in registers; L0 3-buffer pipeline with counted vmcnt + fenced
// issue order; merged one-pass epilogue. See r18 notes.
// ---------------------------------------------------------------------------
#define EW 264    // epilogue LDS row stride in halves (528 B, 16B-aligned)
template <int K, bool FIRST>
__device__ __forceinline__ void gemm_body(
    short* __restrict__ lsh, int bid,
    const __hip_bfloat16* hin,
    const float* __restrict__ x0, const float* __restrict__ x1,
    const float* __restrict__ x2, const float* __restrict__ x3,
    const __hip_bfloat16* __restrict__ wt, const float* __restrict__ bias,
    __hip_bfloat16* zout, __hip_bfloat16* __restrict__ rout) {
    const int t    = threadIdx.x;
    const int w    = t >> 6;
    const int lane = t & 63;
    const int quad = lane >> 4;
    const int l16  = lane & 15;
    const int n0   = bid * 64;

    constexpr int BUFB = FIRST ? 16384 : 8192;   // LDS bytes per stage buffer
    char* const lc = (char*)lsh;

    const __hip_bfloat16* afeat[4];
#pragma unroll
    for (int ft = 0; ft < 4; ++ft)
        afeat[ft] = wt + (size_t)(w * 64 + ft * 16 + l16) * K + quad * 8;

    f32x4 acc[4][4];
#pragma unroll
    for (int ft = 0; ft < 4; ++ft)
#pragma unroll
        for (int nt = 0; nt < 4; ++nt)
            acc[ft][nt] = (f32x4){0.f, 0.f, 0.f, 0.f};

    bf16x8 wreg[2][8];   // [parity][kcl*4+ft] — all indices constant after unroll

    // load the 8 weight fragments of 64-k step p into wreg[pb]
    auto loadW = [&](int p, int pb) {
#pragma unroll
        for (int kcl = 0; kcl < 2; ++kcl)
#pragma unroll
            for (int ft = 0; ft < 4; ++ft)
                wreg[pb][kcl * 4 + ft] =
                    *(const bf16x8*)(afeat[ft] + (p * 2 + kcl) * 32);
    };

    // stage 64-k step p into LDS buffer bb
    auto stage = [&](int p, int bb) {
        char* lb = lc + bb * BUFB;
        if constexpr (FIRST) {
            // one source array per step; row = 64 f32 = 256 B
            const float* sp = (p == 0) ? x0 : (p == 1) ? x1 : (p == 2) ? x2 : x3;
#pragma unroll
            for (int i = 0; i < 4; ++i) {
                const int j   = w * 4 + i;           // 1KB chunk = 4 rows
                const int row = j * 4 + (lane >> 4);
                int rg = n0 + row; if (rg > NN - 1) rg = NN - 1;
                const int colb = ((lane & 15) * 16) ^ ((row & 15) << 4);
                gload16((const char*)sp + (size_t)rg * 256 + colb, lb + j * 1024);
            }
        } else {
            // bf16 row slice = 64 halves = 128 B
#pragma unroll
            for (int i = 0; i < 2; ++i) {
                const int j   = w * 2 + i;           // 1KB chunk = 8 rows
                const int row = j * 8 + (lane >> 3);
                int rg = n0 + row; if (rg > NN - 1) rg = NN - 1;
                const int colb = ((lane & 7) * 16) ^ ((row & 7) << 4);
                gload16((const char*)hin + (size_t)rg * 256 + p * 128 + colb,
                        lb + j * 1024);
            }
        }
    };

    // compute 64-k step s from LDS buffer bb using weight regs wreg[pb]
    auto compute = [&](int s, int bb, int pb) {
        const char* lb = lc + bb * BUFB;
#pragma unroll
        for (int kcl = 0; kcl < 2; ++kcl) {
#pragma unroll
            for (int nt = 0; nt < 4; ++nt) {
                const int row = nt * 16 + l16;
                bf16x8 b;
                if constexpr (FIRST) {
                    const int sw = (row & 15) << 4;
                    const int B0 = kcl * 128 + quad * 32;
                    const char* rb = lb + row * 256;
                    const f32x4 lo = *(const f32x4*)(rb + ((B0) ^ sw));
                    const f32x4 hi = *(const f32x4*)(rb + ((B0 + 16) ^ sw));
                    b[0] = f2bf(lo[0]); b[1] = f2bf(lo[1]);
                    b[2] = f2bf(lo[2]); b[3] = f2bf(lo[3]);
                    b[4] = f2bf(hi[0]); b[5] = f2bf(hi[1]);
                    b[6] = f2bf(hi[2]); b[7] = f2bf(hi[3]);
                } else {
                    const int sw = (row & 7) << 4;
                    const int B0 = kcl * 64 + quad * 16;
                    b = *(const bf16x8*)(lb + row * 128 + (B0 ^ sw));
                }
#pragma unroll
                for (int ft = 0; ft < 4; ++ft)
                    acc[ft][nt] = __builtin_amdgcn_mfma_f32_16x16x32_bf16(
                        wreg[pb][kcl * 4 + ft], b, acc[ft][nt], 0, 0, 0);
            }
        }
    };

    if constexpr (FIRST) {                   // NS=4, 3 LDS buffers
        stage(0, 0); ld_fence();
        stage(1, 1); ld_fence();
        loadW(0, 0); ld_fence();
        wait_vm_bar<12>(); loadW(1, 1); stage(2, 2); compute(0, 0, 0); barrier_only();
        wait_vm_bar<20>(); loadW(2, 0); stage(3, 0); compute(1, 1, 1); barrier_only();
        wait_vm_bar<12>(); loadW(3, 1);              compute(2, 2, 0); barrier_only();
        wait_vm_bar<8>();                            compute(3, 0, 1); barrier_only();
    } else {                                  // NS=2, 2 LDS buffers
        stage(0, 0); ld_fence();
        stage(1, 1); ld_fence();
        loadW(0, 0); loadW(1, 1);
        wait_vm_bar<18>(); compute(0, 0, 0); barrier_only();
        wait_vm_bar<16>(); compute(1, 1, 1); barrier_only();
    }

    // merged epilogue: all 4 waves transpose concurrently into [64][256]
    // (z cols 0..127, r cols 128..255, bias folded into r), one sync, one
    // cooperative store pass.
#pragma unroll
    for (int ft = 0; ft < 4; ++ft) {
        const int fb = ft * 16 + quad * 4;
        float4 bv = make_float4(0.f, 0.f, 0.f, 0.f);
        if (w >= 2) bv = *(const float4*)&bias[(w - 2) * 64 + fb];
        const int cbase = (w & 1) * 64 + ((w >= 2) ? 128 : 0);
#pragma unroll
        for (int nt = 0; nt < 4; ++nt) {
            const f32x4 a = acc[ft][nt];
            bf16x4 p;
            p[0] = f2bf(a[0] + bv.x); p[1] = f2bf(a[1] + bv.y);
            p[2] = f2bf(a[2] + bv.z); p[3] = f2bf(a[3] + bv.w);
            *(bf16x4*)&lsh[(nt * 16 + l16) * EW + cbase + fb] = p;
        }
    }
    __syncthreads();
#pragma unroll
    for (int u = 0; u < 8; ++u) {            // 64 rows x 32 bf16x8-chunks
        const int id  = u * 256 + t;
        const int row = id >> 5, ch = (id & 31) * 8;
        const int nd  = n0 + row;
        if (nd < NN) {
            const bf16x8 v = *(const bf16x8*)&lsh[row * EW + ch];
            if (ch < 128) *(bf16x8*)&zout[(size_t)nd * HH + ch] = v;
            else          *(bf16x8*)&rout[(size_t)nd * HH + (ch - 128)] = v;
        }
    }
}

// plain gemm kernel (layers 1,2): LDS = max(2x8KB dbuf, 64x264x2 epilogue)
template <int K, bool FIRST>
__global__ __launch_bounds__(256) void gemm_kernel(
    const __hip_bfloat16* hin,
    const float* __restrict__ x0, const float* __restrict__ x1,
    const float* __restrict__ x2, const float* __restrict__ x3,
    const __hip_bfloat16* __restrict__ wt, const float* __restrict__ bias,
    __hip_bfloat16* zout, __hip_bfloat16* __restrict__ rout) {
    __shared__ short lsh[16896];
    gemm_body<K, FIRST>(lsh, blockIdx.x, hin, x0, x1, x2, x3, wt, bias, zout, rout);
}

// ---------------------------------------------------------------------------
// Launch 2: edge scatter (blocks [0,SB)) + gemm L0 (blocks [SB, SB+GB)).
// r19: scatter re-decomposed from 391 blocks x 4096 edges to 64 blocks x
// 25000 edges. The old shape issued 391x391 = 153K global atomicAdds to 391
// bcur addresses; each address's 391-deep device-serialized RMW chain
// (~300-400cy each) was a ~60-70us critical path that dominated the whole
// kernel (r1/r3: gemm pipeline rewrites moved nothing). Now: 64 blocks ->
// 64-deep chains (~8-11us), overlapped with the gemm blocks. Edges are read
// twice (count pass + place pass); the 200KB/block range is L2-hot on the
// second pass. Semantics unchanged: blocks reserve disjoint bucket ranges,
// finalize counting-sorts each bucket afterwards.
// ---------------------------------------------------------------------------
__global__ __launch_bounds__(256) void gemm0_scatter_kernel(
    const float* __restrict__ x0, const float* __restrict__ x1,
    const float* __restrict__ x2, const float* __restrict__ x3,
    const __hip_bfloat16* __restrict__ wt, const float* __restrict__ bias,
    __hip_bfloat16* __restrict__ zout, __hip_bfloat16* __restrict__ rout,
    const int* __restrict__ srcv, const int* __restrict__ dstv,
    int* __restrict__ bcur, int* __restrict__ pairs) {
    __shared__ short lsh[24576];               // gemm: 3x16KB dbuf; scatter aliases 3.1KB
    const int t = threadIdx.x;

    if (blockIdx.x >= SB) {
        gemm_body<256, true>(lsh, blockIdx.x - SB, nullptr, x0, x1, x2, x3,
                             wt, bias, zout, rout);
        return;
    }

    int* hist = (int*)lsh;
    int* base = hist + NB;
    for (int j = t; j < NB; j += 256) hist[j] = 0;
    __syncthreads();

    const int e0 = blockIdx.x * EPB;
    // pass 1: per-block bucket histogram
    for (int e = e0 + t; e < e0 + EPB; e += 256)
        atomicAdd(&hist[dstv[e] >> 8], 1);
    __syncthreads();

    // global reservation (one atomic per touched bucket per block)
    for (int j = t; j < NB; j += 256)
        base[j] = hist[j] ? atomicAdd(&bcur[j], hist[j]) : 0;
    __syncthreads();
    for (int j = t; j < NB; j += 256) hist[j] = base[j];   // reuse as cursor
    __syncthreads();

    // pass 2: place packed (src<<8)|dstLow within the reserved ranges
    for (int e = e0 + t; e < e0 + EPB; e += 256) {
        const int s = srcv[e], d = dstv[e];
        const int b = d >> 8;
        const int pos = atomicAdd(&hist[b], 1);
        if (pos < CAP) pairs[b * CAP + pos] = (s << 8) | (d & 255);
    }
}

// ---------------------------------------------------------------------------
// Phase 2: per-bucket counting sort -> csr grouped by node + beg/end/inv.
// ---------------------------------------------------------------------------
__global__ __launch_bounds__(256) void finalize_kernel(
    const int* __restrict__ bcur, const int* __restrict__ pairs,
    int* __restrict__ csr, int* __restrict__ beg, int* __restrict__ eend,
    float* __restrict__ inv) {
    __shared__ int cnt[256];
    __shared__ int scn[256];
    __shared__ int cur[256];
    const int b = blockIdx.x, t = threadIdx.x;
    int m = bcur[b];
    if (m > CAP) m = CAP;

    cnt[t] = 0;
    __syncthreads();
    for (int e = t; e < m; e += 256)
        atomicAdd(&cnt[pairs[b * CAP + e] & 255], 1);
    __syncthreads();

    const int v = cnt[t];
    scn[t] = v;
    __syncthreads();
    for (int st = 1; st < 256; st <<= 1) {
        int tv = (t >= st) ? scn[t - st] : 0;
        __syncthreads();
        scn[t] += tv;
        __syncthreads();
    }
    const int myStart = scn[t] - v;          // exclusive scan
    cur[t] = myStart;
    __syncthreads();

    for (int e = t; e < m; e += 256) {
        const int pk  = pairs[b * CAP + e];
        const int pos = atomicAdd(&cur[pk & 255], 1);
        csr[b * CAP + pos] = pk >> 8;
    }

    const int node = b * 256 + t;
    if (node < NN) {
        beg[node]  = b * CAP + myStart;
        eend[node] = b * CAP + myStart + v;
        inv[node]  = 1.0f / fmaxf((float)v, 1.0f);
    }
}

// ---------------------------------------------------------------------------
// Aggregation + combine: h_out = relu(mean_{in-edges}(z[src]) + r)
// One wave per node; 4 groups x 16 lanes; 16B loads; 4x unroll.
// LAST: fuse layer-3 projection (h3 in f32 regs -> dot Wl3/Wr3 -> z3/r3).
// ---------------------------------------------------------------------------
template <bool LAST>
__global__ __launch_bounds__(256) void aggregate_kernel(
    const __hip_bfloat16* __restrict__ z, __hip_bfloat16* __restrict__ rio,
    const int* __restrict__ beg, const int* __restrict__ eend,
    const int* __restrict__ csr, const float* __restrict__ inv,
    const float* __restrict__ Wl3, const float* __restrict__ Wr3,
    const float* __restrict__ b3, float* __restrict__ z3,
    float* __restrict__ r3) {
    const int i    = (blockIdx.x * 256 + threadIdx.x) >> 6;
    const int lane = threadIdx.x & 63;
    const int g    = lane >> 4;          // edge slot 0..3
    const int l16  = lane & 15;          // 16B chunk within the z row
    if (i >= NN) return;
    const int b0 = beg[i], e0 = eend[i];

    float acc[8];
#pragma unroll
    for (int j = 0; j < 8; ++j) acc[j] = 0.f;

    int e = b0 + g;
    for (; e + 12 < e0; e += 16) {
        const int s0 = csr[e];
        const int s1 = csr[e + 4];
        const int s2 = csr[e + 8];
        const int s3 = csr[e + 12];
        const bf16x8 z0 = *(const bf16x8*)&z[(size_t)s0 * HH + l16 * 8];
        const bf16x8 z1 = *(const bf16x8*)&z[(size_t)s1 * HH + l16 * 8];
        const bf16x8 z2 = *(const bf16x8*)&z[(size_t)s2 * HH + l16 * 8];
        const bf16x8 z3v = *(const bf16x8*)&z[(size_t)s3 * HH + l16 * 8];
        const __hip_bfloat162* p0 = (const __hip_bfloat162*)&z0;
        const __hip_bfloat162* p1 = (const __hip_bfloat162*)&z1;
        const __hip_bfloat162* p2 = (const __hip_bfloat162*)&z2;
        const __hip_bfloat162* p3 = (const __hip_bfloat162*)&z3v;
#pragma unroll
        for (int j = 0; j < 4; ++j) {
            acc[2 * j]     += __bfloat162float(p0[j].x) + __bfloat162float(p1[j].x)
                            + __bfloat162float(p2[j].x) + __bfloat162float(p3[j].x);
            acc[2 * j + 1] += __bfloat162float(p0[j].y) + __bfloat162float(p1[j].y)
                            + __bfloat162float(p2[j].y) + __bfloat162float(p3[j].y);
        }
    }
    for (; e < e0; e += 4) {
        const int s0 = csr[e];
        const bf16x8 z0 = *(const bf16x8*)&z[(size_t)s0 * HH + l16 * 8];
        const __hip_bfloat162* p0 = (const __hip_bfloat162*)&z0;
#pragma unroll
        for (int j = 0; j < 4; ++j) {
            acc[2 * j]     += __bfloat162float(p0[j].x);
            acc[2 * j + 1] += __bfloat162float(p0[j].y);
        }
    }

#pragma unroll
    for (int j = 0; j < 8; ++j) {
        acc[j] += __shfl_xor(acc[j], 16, 64);
        acc[j] += __shfl_xor(acc[j], 32, 64);
    }

    const float iv = inv[i];
    const int   f  = l16 * 8 + g * 2;
    const __hip_bfloat162 rv = *(const __hip_bfloat162*)&rio[(size_t)i * HH + f];
    const float ox = fmaxf(acc[g * 2]     * iv + __bfloat162float(rv.x), 0.f);
    const float oy = fmaxf(acc[g * 2 + 1] * iv + __bfloat162float(rv.y), 0.f);

    if (!LAST) {
        __hip_bfloat162 o;
        o.x = __float2bfloat16(ox);
        o.y = __float2bfloat16(oy);
        *(__hip_bfloat162*)&rio[(size_t)i * HH + f] = o;
    } else {
        const float2 wl = *(const float2*)&Wl3[f];
        const float2 wr = *(const float2*)&Wr3[f];
        float al = ox * wl.x + oy * wl.y;
        float ar = ox * wr.x + oy * wr.y;
#pragma unroll
        for (int m = 32; m; m >>= 1) {
            al += __shfl_xor(al, m, 64);
            ar += __shfl_xor(ar, m, 64);
        }
        if (lane == 0) {
            z3[i] = al;
            r3[i] = ar + b3[0];
        }
    }
}

// Final: out[i] = sigmoid(mean(z3[src]) + r3[i]); per-block partial sums
__global__ __launch_bounds__(256) void final_kernel(
    const float* __restrict__ z3, const float* __restrict__ r3,
    const int* __restrict__ beg, const int* __restrict__ eend,
    const int* __restrict__ csr, const float* __restrict__ inv,
    float* __restrict__ out, float* __restrict__ partial) {
    __shared__ float red[4];
    const int i    = (blockIdx.x * 256 + threadIdx.x) >> 6;
    const int lane = threadIdx.x & 63;
    const int w    = threadIdx.x >> 6;
    float v = 0.f;
    if (i < NN) {
        const int b0 = beg[i], e0 = eend[i];
        float a = 0.f;
        for (int e = b0 + lane; e < e0; e += 64) a += z3[csr[e]];
#pragma unroll
        for (int m = 32; m; m >>= 1) a += __shfl_xor(a, m, 64);
        const float pre = a * inv[i] + r3[i];
        const float s = 1.f / (1.f + __expf(-pre));
        if (lane == 0) { out[i] = s; v = s; }
    }
    if (lane == 0) red[w] = v;
    __syncthreads();
    if (threadIdx.x == 0)
        partial[blockIdx.x] = red[0] + red[1] + red[2] + red[3];
}

__global__ __launch_bounds__(256) void mean_kernel(const float* __restrict__ partial,
                                                   int nb, float* __restrict__ out) {
    __shared__ float lds[256];
    float s = 0.f;
    for (int i = threadIdx.x; i < nb; i += 256) s += partial[i];
    lds[threadIdx.x] = s;
    __syncthreads();
    for (int st = 128; st; st >>= 1) {
        if (threadIdx.x < st) lds[threadIdx.x] += lds[threadIdx.x + st];
        __syncthreads();
    }
    if (threadIdx.x == 0) out[NN] = lds[0] / (float)NN;
}

// ---------------------------------------------------------------------------
extern "C" void kernel_launch(void* const* d_in, const int* in_sizes, int n_in,
                              void* d_out, int out_size, void* d_ws, size_t ws_size,
                              hipStream_t stream) {
    const float* x    = (const float*)d_in[0];
    const float* diff = (const float*)d_in[1];
    const float* rec  = (const float*)d_in[2];
    const float* hid  = (const float*)d_in[3];
    const int* edge   = (const int*)d_in[4];
    const int* esrc = edge;        // row 0
    const int* edst = edge + EE;   // row 1
    const float* Wl0 = (const float*)d_in[5];
    const float* Wr0 = (const float*)d_in[6];
    const float* b0  = (const float*)d_in[7];
    const float* Wl1 = (const float*)d_in[8];
    const float* Wr1 = (const float*)d_in[9];
    const float* b1  = (const float*)d_in[10];
    const float* Wl2 = (const float*)d_in[11];
    const float* Wr2 = (const float*)d_in[12];
    const float* b2  = (const float*)d_in[13];
    const float* Wl3 = (const float*)d_in[14];
    const float* Wr3 = (const float*)d_in[15];
    const float* b3  = (const float*)d_in[16];
    float* out = (float*)d_out;

    // workspace carve-out (256B aligned) — total ~70 MB
    char* w = (char*)d_ws;
    auto alloc = [&](size_t bytes) -> void* {
        void* p = (void*)w;
        w += (bytes + 255) & ~(size_t)255;
        return p;
    };
    __hip_bfloat16* bufA = (__hip_bfloat16*)alloc((size_t)NN * HH * 2);  // 25.6 MB
    __hip_bfloat16* bufB = (__hip_bfloat16*)alloc((size_t)NN * HH * 2);  // 25.6 MB
    __hip_bfloat16* WT0  = (__hip_bfloat16*)alloc((size_t)256 * 256 * 2);
    __hip_bfloat16* WT1  = (__hip_bfloat16*)alloc((size_t)256 * 128 * 2);
    __hip_bfloat16* WT2  = (__hip_bfloat16*)alloc((size_t)256 * 128 * 2);
    int*   pairs   = (int*)alloc((size_t)NB * CAP * 4);                  // 8.0 MB
    int*   csr     = (int*)alloc((size_t)NB * CAP * 4);                  // 8.0 MB
    int*   bcur    = (int*)alloc((size_t)512 * 4);
    int*   beg     = (int*)alloc((size_t)NN * 4);
    int*   eend    = (int*)alloc((size_t)NN * 4);
    float* inv     = (float*)alloc((size_t)NN * 4);
    float* z3      = (float*)alloc((size_t)NN * 4);
    float* r3      = (float*)alloc((size_t)NN * 4);
    float* partial = (float*)alloc((size_t)25000 * 4);

    const int WB = (NN + 3) / 4;             // 25000 (1 node/wave)

    // Launch 1: weight prep + zero cursors (independent, tiny)
    prep_kernel<<<129, 1024, 0, stream>>>(Wl0, Wr0, Wl1, Wr1, Wl2, Wr2,
                                          WT0, WT1, WT2, bcur);

    // Launch 2: edge scatter (first SB blocks) overlapped with gemm L0
    gemm0_scatter_kernel<<<GB + SB, 256, 0, stream>>>(
        x, diff, rec, hid, WT0, b0, bufA, bufB, esrc, edst, bcur, pairs);

    // Launch 3: finalize CSR (needs scatter)
    finalize_kernel<<<NB, 256, 0, stream>>>(bcur, pairs, csr, beg, eend, inv);

    // agg L0: h1 -> B (over r)
    aggregate_kernel<false><<<WB, 256, 0, stream>>>(bufA, bufB, beg, eend, csr, inv,
                                                    nullptr, nullptr, nullptr,
                                                    nullptr, nullptr);

    // L1: h in B; z in-place -> B, r -> A; agg: h2 -> A
    gemm_kernel<128, false><<<GB, 256, 0, stream>>>(bufB, nullptr, nullptr, nullptr, nullptr,
                                                    WT1, b1, bufB, bufA);
    aggregate_kernel<false><<<WB, 256, 0, stream>>>(bufB, bufA, beg, eend, csr, inv,
                                                    nullptr, nullptr, nullptr,
                                                    nullptr, nullptr);

    // L2: h in A; z in-place -> A, r -> B; agg(LAST): fused proj3 -> z3, r3
    gemm_kernel<128, false><<<GB, 256, 0, stream>>>(bufA, nullptr, nullptr, nullptr, nullptr,
                                                    WT2, b2, bufA, bufB);
    aggregate_kernel<true><<<WB, 256, 0, stream>>>(bufA, bufB, beg, eend, csr, inv,
                                                   Wl3, Wr3, b3, z3, r3);

    // final: aggregate scalars, sigmoid + mean
    final_kernel<<<WB, 256, 0, stream>>>(z3, r3, beg, eend, csr, inv, out, partial);
    mean_kernel<<<1, 256, 0, stream>>>(partial, WB, out);
}

// Round 5
// 497.690 us; speedup vs baseline: 1.1398x; 1.1398x over previous
//
#include <hip/hip_runtime.h>
#include <hip/hip_bf16.h>

// Problem constants (fixed by reference)
#define NN 100000
#define EE 1600000
#define HH 128
#define NB 391      // buckets = ceil(NN/256)
#define CAP 5120    // padded bucket capacity (mean 4096, sigma 64 -> +16 sigma)
#define GB 1563     // gemm blocks = ceil(NN/64)
#define SB 64       // scatter blocks. r19 analysis: reservation atomics to each
                    // bcur[j] serialize chain-depth x ~450cy device RMW. Depth
                    // 391 (old) = ~73us — THE invariant critical path of r0-r3.
                    // Depth 64 = ~12us, overlapped with gemm blocks.
#define EPB (EE / SB)   // 25000 edges per scatter block (exact)

typedef short bf16x8 __attribute__((ext_vector_type(8)));
typedef short bf16x4 __attribute__((ext_vector_type(4)));
typedef float f32x4  __attribute__((ext_vector_type(4)));

__device__ inline short f2bf(float v) {
    __hip_bfloat16 b = __float2bfloat16(v);
    return *reinterpret_cast<short*>(&b);
}

// direct global->LDS staging (16B per lane, LDS dest = uniform base + lane*16)
typedef __attribute__((address_space(1))) void gvoid_t;
typedef __attribute__((address_space(3))) void svoid_t;
__device__ __forceinline__ void gload16(const void* g, void* l) {
    __builtin_amdgcn_global_load_lds((gvoid_t*)g, (svoid_t*)l, 16, 0, 0);
}

// Compiler-order fence: pins the ISSUE ORDER of vmem groups so the counted
// vmcnt arithmetic below is valid (r2 lesson: inline-asm waitcnt orders the
// HW, not the compiler).
__device__ __forceinline__ void ld_fence() { asm volatile("" ::: "memory"); }

// counted-vmcnt barrier: wait own outstanding vmem down to N, then raw
// s_barrier. N derived from the fenced issue order in gemm_body.
template <int N>
__device__ __forceinline__ void wait_vm_bar() {
    if constexpr (N == 0)
        asm volatile("s_waitcnt vmcnt(0)\n\ts_barrier" ::: "memory");
    else if constexpr (N == 8)
        asm volatile("s_waitcnt vmcnt(8)\n\ts_barrier" ::: "memory");
    else if constexpr (N == 12)
        asm volatile("s_waitcnt vmcnt(12)\n\ts_barrier" ::: "memory");
    else if constexpr (N == 16)
        asm volatile("s_waitcnt vmcnt(16)\n\ts_barrier" ::: "memory");
    else if constexpr (N == 18)
        asm volatile("s_waitcnt vmcnt(18)\n\ts_barrier" ::: "memory");
    else if constexpr (N == 20)
        asm volatile("s_waitcnt vmcnt(20)\n\ts_barrier" ::: "memory");
    else
        static_assert(N == 0 || N == 8 || N == 12 || N == 16 || N == 18 || N == 20,
                      "bad N");
}
__device__ __forceinline__ void barrier_only() {
    asm volatile("s_barrier" ::: "memory");
}

// ---------------------------------------------------------------------------
// Launch 1: weight prep (blocks 0..127) + zero bucket cursors (block 128)
// ---------------------------------------------------------------------------
__global__ __launch_bounds__(1024) void prep_kernel(
    const float* __restrict__ Wl0, const float* __restrict__ Wr0,
    const float* __restrict__ Wl1, const float* __restrict__ Wr1,
    const float* __restrict__ Wl2, const float* __restrict__ Wr2,
    __hip_bfloat16* __restrict__ WT0, __hip_bfloat16* __restrict__ WT1,
    __hip_bfloat16* __restrict__ WT2, int* __restrict__ bcur) {
    const int t = threadIdx.x;
    if (blockIdx.x == 128) {
        if (t < NB) bcur[t] = 0;
        return;
    }
    int id = blockIdx.x * 1024 + t;              // 0 .. 131071
    if (id < 65536) {                            // layer 0: K=256
        int k = id & 255, n = id >> 8;
        float v = (n < 128) ? Wl0[(size_t)k * 128 + n]
                            : Wr0[(size_t)k * 128 + (n - 128)];
        WT0[(size_t)n * 256 + k] = __float2bfloat16(v);
    } else {
        id -= 65536;
        int layer = id >> 15;                    // 0 -> L1, 1 -> L2
        int u = id & 32767;
        int k = u & 127, n = u >> 7;
        const float* Wl = layer ? Wl2 : Wl1;
        const float* Wr = layer ? Wr2 : Wr1;
        __hip_bfloat16* WT = layer ? WT2 : WT1;
        float v = (n < 128) ? Wl[(size_t)k * 128 + n]
                            : Wr[(size_t)k * 128 + (n - 128)];
        WT[(size_t)n * 128 + k] = __float2bfloat16(v);
    }
}

// ---------------------------------------------------------------------------
// MFMA GEMM body (r18, unchanged): [z | r] = h @ [Wl|Wr], 64-row tile, 4 waves.
// Weights in registers; L0 3-buffer pipeline with counted vmcnt + fenced
// issue order; merged one-pass epilogue. See r18 notes.
// ---------------------------------------------------------------------------
#define EW 264    // epilogue LDS row stride in halves (528 B, 16B-aligned)
template <int K, bool FIRST>
__device__ __forceinline__ void gemm_body(
    short* __restrict__ lsh, int bid,
    const __hip_bfloat16* hin,
    const float* __restrict__ x0, const float* __restrict__ x1,
    const float* __restrict__ x2, const float* __restrict__ x3,
    const __hip_bfloat16* __restrict__ wt, const float* __restrict__ bias,
    __hip_bfloat16* zout, __hip_bfloat16* __restrict__ rout) {
    const int t    = threadIdx.x;
    const int w    = t >> 6;
    const int lane = t & 63;
    const int quad = lane >> 4;
    const int l16  = lane & 15;
    const int n0   = bid * 64;

    constexpr int BUFB = FIRST ? 16384 : 8192;   // LDS bytes per stage buffer
    char* const lc = (char*)lsh;

    const __hip_bfloat16* afeat[4];
#pragma unroll
    for (int ft = 0; ft < 4; ++ft)
        afeat[ft] = wt + (size_t)(w * 64 + ft * 16 + l16) * K + quad * 8;

    f32x4 acc[4][4];
#pragma unroll
    for (int ft = 0; ft < 4; ++ft)
#pragma unroll
        for (int nt = 0; nt < 4; ++nt)
            acc[ft][nt] = (f32x4){0.f, 0.f, 0.f, 0.f};

    bf16x8 wreg[2][8];   // [parity][kcl*4+ft] — all indices constant after unroll

    // load the 8 weight fragments of 64-k step p into wreg[pb]
    auto loadW = [&](int p, int pb) {
#pragma unroll
        for (int kcl = 0; kcl < 2; ++kcl)
#pragma unroll
            for (int ft = 0; ft < 4; ++ft)
                wreg[pb][kcl * 4 + ft] =
                    *(const bf16x8*)(afeat[ft] + (p * 2 + kcl) * 32);
    };

    // stage 64-k step p into LDS buffer bb
    auto stage = [&](int p, int bb) {
        char* lb = lc + bb * BUFB;
        if constexpr (FIRST) {
            // one source array per step; row = 64 f32 = 256 B
            const float* sp = (p == 0) ? x0 : (p == 1) ? x1 : (p == 2) ? x2 : x3;
#pragma unroll
            for (int i = 0; i < 4; ++i) {
                const int j   = w * 4 + i;           // 1KB chunk = 4 rows
                const int row = j * 4 + (lane >> 4);
                int rg = n0 + row; if (rg > NN - 1) rg = NN - 1;
                const int colb = ((lane & 15) * 16) ^ ((row & 15) << 4);
                gload16((const char*)sp + (size_t)rg * 256 + colb, lb + j * 1024);
            }
        } else {
            // bf16 row slice = 64 halves = 128 B
#pragma unroll
            for (int i = 0; i < 2; ++i) {
                const int j   = w * 2 + i;           // 1KB chunk = 8 rows
                const int row = j * 8 + (lane >> 3);
                int rg = n0 + row; if (rg > NN - 1) rg = NN - 1;
                const int colb = ((lane & 7) * 16) ^ ((row & 7) << 4);
                gload16((const char*)hin + (size_t)rg * 256 + p * 128 + colb,
                        lb + j * 1024);
            }
        }
    };

    // compute 64-k step s from LDS buffer bb using weight regs wreg[pb]
    auto compute = [&](int s, int bb, int pb) {
        const char* lb = lc + (bb)*BUFB;
#pragma unroll
        for (int kcl = 0; kcl < 2; ++kcl) {
#pragma unroll
            for (int nt = 0; nt < 4; ++nt) {
                const int row = nt * 16 + l16;
                bf16x8 b;
                if constexpr (FIRST) {
                    const int sw = (row & 15) << 4;
                    const int B0 = kcl * 128 + quad * 32;
                    const char* rb = lb + row * 256;
                    const f32x4 lo = *(const f32x4*)(rb + ((B0) ^ sw));
                    const f32x4 hi = *(const f32x4*)(rb + ((B0 + 16) ^ sw));
                    b[0] = f2bf(lo[0]); b[1] = f2bf(lo[1]);
                    b[2] = f2bf(lo[2]); b[3] = f2bf(lo[3]);
                    b[4] = f2bf(hi[0]); b[5] = f2bf(hi[1]);
                    b[6] = f2bf(hi[2]); b[7] = f2bf(hi[3]);
                } else {
                    const int sw = (row & 7) << 4;
                    const int B0 = kcl * 64 + quad * 16;
                    b = *(const bf16x8*)(lb + row * 128 + (B0 ^ sw));
                }
#pragma unroll
                for (int ft = 0; ft < 4; ++ft)
                    acc[ft][nt] = __builtin_amdgcn_mfma_f32_16x16x32_bf16(
                        wreg[pb][kcl * 4 + ft], b, acc[ft][nt], 0, 0, 0);
            }
        }
    };

    if constexpr (FIRST) {                   // NS=4, 3 LDS buffers
        stage(0, 0); ld_fence();
        stage(1, 1); ld_fence();
        loadW(0, 0); ld_fence();
        wait_vm_bar<12>(); loadW(1, 1); stage(2, 2); compute(0, 0, 0); barrier_only();
        wait_vm_bar<20>(); loadW(2, 0); stage(3, 0); compute(1, 1, 1); barrier_only();
        wait_vm_bar<12>(); loadW(3, 1);              compute(2, 2, 0); barrier_only();
        wait_vm_bar<8>();                            compute(3, 0, 1); barrier_only();
    } else {                                  // NS=2, 2 LDS buffers
        stage(0, 0); ld_fence();
        stage(1, 1); ld_fence();
        loadW(0, 0); loadW(1, 1);
        wait_vm_bar<18>(); compute(0, 0, 0); barrier_only();
        wait_vm_bar<16>(); compute(1, 1, 1); barrier_only();
    }

    // merged epilogue: all 4 waves transpose concurrently into [64][256]
    // (z cols 0..127, r cols 128..255, bias folded into r), one sync, one
    // cooperative store pass.
#pragma unroll
    for (int ft = 0; ft < 4; ++ft) {
        const int fb = ft * 16 + quad * 4;
        float4 bv = make_float4(0.f, 0.f, 0.f, 0.f);
        if (w >= 2) bv = *(const float4*)&bias[(w - 2) * 64 + fb];
        const int cbase = (w & 1) * 64 + ((w >= 2) ? 128 : 0);
#pragma unroll
        for (int nt = 0; nt < 4; ++nt) {
            const f32x4 a = acc[ft][nt];
            bf16x4 p;
            p[0] = f2bf(a[0] + bv.x); p[1] = f2bf(a[1] + bv.y);
            p[2] = f2bf(a[2] + bv.z); p[3] = f2bf(a[3] + bv.w);
            *(bf16x4*)&lsh[(nt * 16 + l16) * EW + cbase + fb] = p;
        }
    }
    __syncthreads();
#pragma unroll
    for (int u = 0; u < 8; ++u) {            // 64 rows x 32 bf16x8-chunks
        const int id  = u * 256 + t;
        const int row = id >> 5, ch = (id & 31) * 8;
        const int nd  = n0 + row;
        if (nd < NN) {
            const bf16x8 v = *(const bf16x8*)&lsh[row * EW + ch];
            if (ch < 128) *(bf16x8*)&zout[(size_t)nd * HH + ch] = v;
            else          *(bf16x8*)&rout[(size_t)nd * HH + (ch - 128)] = v;
        }
    }
}

// plain gemm kernel (layers 1,2): LDS = max(2x8KB dbuf, 64x264x2 epilogue)
template <int K, bool FIRST>
__global__ __launch_bounds__(256) void gemm_kernel(
    const __hip_bfloat16* hin,
    const float* __restrict__ x0, const float* __restrict__ x1,
    const float* __restrict__ x2, const float* __restrict__ x3,
    const __hip_bfloat16* __restrict__ wt, const float* __restrict__ bias,
    __hip_bfloat16* zout, __hip_bfloat16* __restrict__ rout) {
    __shared__ short lsh[16896];
    gemm_body<K, FIRST>(lsh, blockIdx.x, hin, x0, x1, x2, x3, wt, bias, zout, rout);
}

// ---------------------------------------------------------------------------
// Launch 2: edge scatter (blocks [0,SB)) + gemm L0 (blocks [SB, SB+GB)).
// r20 scatter: SB=64 fat blocks (short reservation chains) WITH 16-deep
// register-blocked edge loads in both passes (r4 regression root-cause: the
// fat-block rewrite used plain loops -> one exposed ~600cy load latency per
// iteration; r3's s[16]/d[16] unroll kept 16 loads in flight).
// Pass 1: dst-only histogram. Reservation: one global atomic per touched
// bucket (chain depth 64 = ~12us, overlapped). Pass 2: re-read src/dst
// (L2-hot), place packed (src<<8)|dstLow in reserved ranges.
// ---------------------------------------------------------------------------
__global__ __launch_bounds__(256) void gemm0_scatter_kernel(
    const float* __restrict__ x0, const float* __restrict__ x1,
    const float* __restrict__ x2, const float* __restrict__ x3,
    const __hip_bfloat16* __restrict__ wt, const float* __restrict__ bias,
    __hip_bfloat16* __restrict__ zout, __hip_bfloat16* __restrict__ rout,
    const int* __restrict__ srcv, const int* __restrict__ dstv,
    int* __restrict__ bcur, int* __restrict__ pairs) {
    __shared__ short lsh[24576];               // gemm: 3x16KB dbuf; scatter aliases 3.1KB
    const int t = threadIdx.x;

    if (blockIdx.x >= SB) {
        gemm_body<256, true>(lsh, blockIdx.x - SB, nullptr, x0, x1, x2, x3,
                             wt, bias, zout, rout);
        return;
    }

    int* hist = (int*)lsh;
    int* base = hist + NB;
    for (int j = t; j < NB; j += 256) hist[j] = 0;
    __syncthreads();

    const int e0   = blockIdx.x * EPB;
    const int eend_ = e0 + EPB;

    // pass 1: per-block bucket histogram (16-deep register-blocked loads)
    for (int be = e0; be < eend_; be += 4096) {
        int d[16];
#pragma unroll
        for (int u = 0; u < 16; ++u) {
            const int e = be + u * 256 + t;
            d[u] = (e < eend_) ? dstv[e] : -1;
        }
#pragma unroll
        for (int u = 0; u < 16; ++u)
            if (d[u] >= 0) atomicAdd(&hist[d[u] >> 8], 1);
    }
    __syncthreads();

    // global reservation (one atomic per touched bucket; 64-deep chains)
    for (int j = t; j < NB; j += 256)
        base[j] = hist[j] ? atomicAdd(&bcur[j], hist[j]) : 0;
    __syncthreads();
    for (int j = t; j < NB; j += 256) hist[j] = base[j];   // reuse as cursor
    __syncthreads();

    // pass 2: place packed (src<<8)|dstLow within the reserved ranges
    for (int be = e0; be < eend_; be += 4096) {
        int s[16], d[16];
#pragma unroll
        for (int u = 0; u < 16; ++u) {
            const int e = be + u * 256 + t;
            if (e < eend_) { s[u] = srcv[e]; d[u] = dstv[e]; }
            else d[u] = -1;
        }
#pragma unroll
        for (int u = 0; u < 16; ++u)
            if (d[u] >= 0) {
                const int b   = d[u] >> 8;
                const int pos = atomicAdd(&hist[b], 1);
                if (pos < CAP) pairs[b * CAP + pos] = (s[u] << 8) | (d[u] & 255);
            }
    }
}

// ---------------------------------------------------------------------------
// Phase 2: per-bucket counting sort -> csr grouped by node + beg/end/inv.
// ---------------------------------------------------------------------------
__global__ __launch_bounds__(256) void finalize_kernel(
    const int* __restrict__ bcur, const int* __restrict__ pairs,
    int* __restrict__ csr, int* __restrict__ beg, int* __restrict__ eend,
    float* __restrict__ inv) {
    __shared__ int cnt[256];
    __shared__ int scn[256];
    __shared__ int cur[256];
    const int b = blockIdx.x, t = threadIdx.x;
    int m = bcur[b];
    if (m > CAP) m = CAP;

    cnt[t] = 0;
    __syncthreads();
    for (int e = t; e < m; e += 256)
        atomicAdd(&cnt[pairs[b * CAP + e] & 255], 1);
    __syncthreads();

    const int v = cnt[t];
    scn[t] = v;
    __syncthreads();
    for (int st = 1; st < 256; st <<= 1) {
        int tv = (t >= st) ? scn[t - st] : 0;
        __syncthreads();
        scn[t] += tv;
        __syncthreads();
    }
    const int myStart = scn[t] - v;          // exclusive scan
    cur[t] = myStart;
    __syncthreads();

    for (int e = t; e < m; e += 256) {
        const int pk  = pairs[b * CAP + e];
        const int pos = atomicAdd(&cur[pk & 255], 1);
        csr[b * CAP + pos] = pk >> 8;
    }

    const int node = b * 256 + t;
    if (node < NN) {
        beg[node]  = b * CAP + myStart;
        eend[node] = b * CAP + myStart + v;
        inv[node]  = 1.0f / fmaxf((float)v, 1.0f);
    }
}

// ---------------------------------------------------------------------------
// Aggregation + combine: h_out = relu(mean_{in-edges}(z[src]) + r)
// One wave per node; 4 groups x 16 lanes; 16B loads; 4x unroll.
// LAST: fuse layer-3 projection (h3 in f32 regs -> dot Wl3/Wr3 -> z3/r3).
// ---------------------------------------------------------------------------
template <bool LAST>
__global__ __launch_bounds__(256) void aggregate_kernel(
    const __hip_bfloat16* __restrict__ z, __hip_bfloat16* __restrict__ rio,
    const int* __restrict__ beg, const int* __restrict__ eend,
    const int* __restrict__ csr, const float* __restrict__ inv,
    const float* __restrict__ Wl3, const float* __restrict__ Wr3,
    const float* __restrict__ b3, float* __restrict__ z3,
    float* __restrict__ r3) {
    const int i    = (blockIdx.x * 256 + threadIdx.x) >> 6;
    const int lane = threadIdx.x & 63;
    const int g    = lane >> 4;          // edge slot 0..3
    const int l16  = lane & 15;          // 16B chunk within the z row
    if (i >= NN) return;
    const int b0 = beg[i], e0 = eend[i];

    float acc[8];
#pragma unroll
    for (int j = 0; j < 8; ++j) acc[j] = 0.f;

    int e = b0 + g;
    for (; e + 12 < e0; e += 16) {
        const int s0 = csr[e];
        const int s1 = csr[e + 4];
        const int s2 = csr[e + 8];
        const int s3 = csr[e + 12];
        const bf16x8 z0 = *(const bf16x8*)&z[(size_t)s0 * HH + l16 * 8];
        const bf16x8 z1 = *(const bf16x8*)&z[(size_t)s1 * HH + l16 * 8];
        const bf16x8 z2 = *(const bf16x8*)&z[(size_t)s2 * HH + l16 * 8];
        const bf16x8 z3v = *(const bf16x8*)&z[(size_t)s3 * HH + l16 * 8];
        const __hip_bfloat162* p0 = (const __hip_bfloat162*)&z0;
        const __hip_bfloat162* p1 = (const __hip_bfloat162*)&z1;
        const __hip_bfloat162* p2 = (const __hip_bfloat162*)&z2;
        const __hip_bfloat162* p3 = (const __hip_bfloat162*)&z3v;
#pragma unroll
        for (int j = 0; j < 4; ++j) {
            acc[2 * j]     += __bfloat162float(p0[j].x) + __bfloat162float(p1[j].x)
                            + __bfloat162float(p2[j].x) + __bfloat162float(p3[j].x);
            acc[2 * j + 1] += __bfloat162float(p0[j].y) + __bfloat162float(p1[j].y)
                            + __bfloat162float(p2[j].y) + __bfloat162float(p3[j].y);
        }
    }
    for (; e < e0; e += 4) {
        const int s0 = csr[e];
        const bf16x8 z0 = *(const bf16x8*)&z[(size_t)s0 * HH + l16 * 8];
        const __hip_bfloat162* p0 = (const __hip_bfloat162*)&z0;
#pragma unroll
        for (int j = 0; j < 4; ++j) {
            acc[2 * j]     += __bfloat162float(p0[j].x);
            acc[2 * j + 1] += __bfloat162float(p0[j].y);
        }
    }

#pragma unroll
    for (int j = 0; j < 8; ++j) {
        acc[j] += __shfl_xor(acc[j], 16, 64);
        acc[j] += __shfl_xor(acc[j], 32, 64);
    }

    const float iv = inv[i];
    const int   f  = l16 * 8 + g * 2;
    const __hip_bfloat162 rv = *(const __hip_bfloat162*)&rio[(size_t)i * HH + f];
    const float ox = fmaxf(acc[g * 2]     * iv + __bfloat162float(rv.x), 0.f);
    const float oy = fmaxf(acc[g * 2 + 1] * iv + __bfloat162float(rv.y), 0.f);

    if (!LAST) {
        __hip_bfloat162 o;
        o.x = __float2bfloat16(ox);
        o.y = __float2bfloat16(oy);
        *(__hip_bfloat162*)&rio[(size_t)i * HH + f] = o;
    } else {
        const float2 wl = *(const float2*)&Wl3[f];
        const float2 wr = *(const float2*)&Wr3[f];
        float al = ox * wl.x + oy * wl.y;
        float ar = ox * wr.x + oy * wr.y;
#pragma unroll
        for (int m = 32; m; m >>= 1) {
            al += __shfl_xor(al, m, 64);
            ar += __shfl_xor(ar, m, 64);
        }
        if (lane == 0) {
            z3[i] = al;
            r3[i] = ar + b3[0];
        }
    }
}

// Final: out[i] = sigmoid(mean(z3[src]) + r3[i]); per-block partial sums
__global__ __launch_bounds__(256) void final_kernel(
    const float* __restrict__ z3, const float* __restrict__ r3,
    const int* __restrict__ beg, const int* __restrict__ eend,
    const int* __restrict__ csr, const float* __restrict__ inv,
    float* __restrict__ out, float* __restrict__ partial) {
    __shared__ float red[4];
    const int i    = (blockIdx.x * 256 + threadIdx.x) >> 6;
    const int lane = threadIdx.x & 63;
    const int w    = threadIdx.x >> 6;
    float v = 0.f;
    if (i < NN) {
        const int b0 = beg[i], e0 = eend[i];
        float a = 0.f;
        for (int e = b0 + lane; e < e0; e += 64) a += z3[csr[e]];
#pragma unroll
        for (int m = 32; m; m >>= 1) a += __shfl_xor(a, m, 64);
        const float pre = a * inv[i] + r3[i];
        const float s = 1.f / (1.f + __expf(-pre));
        if (lane == 0) { out[i] = s; v = s; }
    }
    if (lane == 0) red[w] = v;
    __syncthreads();
    if (threadIdx.x == 0)
        partial[blockIdx.x] = red[0] + red[1] + red[2] + red[3];
}

__global__ __launch_bounds__(256) void mean_kernel(const float* __restrict__ partial,
                                                   int nb, float* __restrict__ out) {
    __shared__ float lds[256];
    float s = 0.f;
    for (int i = threadIdx.x; i < nb; i += 256) s += partial[i];
    lds[threadIdx.x] = s;
    __syncthreads();
    for (int st = 128; st; st >>= 1) {
        if (threadIdx.x < st) lds[threadIdx.x] += lds[threadIdx.x + st];
        __syncthreads();
    }
    if (threadIdx.x == 0) out[NN] = lds[0] / (float)NN;
}

// ---------------------------------------------------------------------------
extern "C" void kernel_launch(void* const* d_in, const int* in_sizes, int n_in,
                              void* d_out, int out_size, void* d_ws, size_t ws_size,
                              hipStream_t stream) {
    const float* x    = (const float*)d_in[0];
    const float* diff = (const float*)d_in[1];
    const float* rec  = (const float*)d_in[2];
    const float* hid  = (const float*)d_in[3];
    const int* edge   = (const int*)d_in[4];
    const int* esrc = edge;        // row 0
    const int* edst = edge + EE;   // row 1
    const float* Wl0 = (const float*)d_in[5];
    const float* Wr0 = (const float*)d_in[6];
    const float* b0  = (const float*)d_in[7];
    const float* Wl1 = (const float*)d_in[8];
    const float* Wr1 = (const float*)d_in[9];
    const float* b1  = (const float*)d_in[10];
    const float* Wl2 = (const float*)d_in[11];
    const float* Wr2 = (const float*)d_in[12];
    const float* b2  = (const float*)d_in[13];
    const float* Wl3 = (const float*)d_in[14];
    const float* Wr3 = (const float*)d_in[15];
    const float* b3  = (const float*)d_in[16];
    float* out = (float*)d_out;

    // workspace carve-out (256B aligned) — total ~70 MB
    char* w = (char*)d_ws;
    auto alloc = [&](size_t bytes) -> void* {
        void* p = (void*)w;
        w += (bytes + 255) & ~(size_t)255;
        return p;
    };
    __hip_bfloat16* bufA = (__hip_bfloat16*)alloc((size_t)NN * HH * 2);  // 25.6 MB
    __hip_bfloat16* bufB = (__hip_bfloat16*)alloc((size_t)NN * HH * 2);  // 25.6 MB
    __hip_bfloat16* WT0  = (__hip_bfloat16*)alloc((size_t)256 * 256 * 2);
    __hip_bfloat16* WT1  = (__hip_bfloat16*)alloc((size_t)256 * 128 * 2);
    __hip_bfloat16* WT2  = (__hip_bfloat16*)alloc((size_t)256 * 128 * 2);
    int*   pairs   = (int*)alloc((size_t)NB * CAP * 4);                  // 8.0 MB
    int*   csr     = (int*)alloc((size_t)NB * CAP * 4);                  // 8.0 MB
    int*   bcur    = (int*)alloc((size_t)512 * 4);
    int*   beg     = (int*)alloc((size_t)NN * 4);
    int*   eend    = (int*)alloc((size_t)NN * 4);
    float* inv     = (float*)alloc((size_t)NN * 4);
    float* z3      = (float*)alloc((size_t)NN * 4);
    float* r3      = (float*)alloc((size_t)NN * 4);
    float* partial = (float*)alloc((size_t)25000 * 4);

    const int WB = (NN + 3) / 4;             // 25000 (1 node/wave)

    // Launch 1: weight prep + zero cursors (independent, tiny)
    prep_kernel<<<129, 1024, 0, stream>>>(Wl0, Wr0, Wl1, Wr1, Wl2, Wr2,
                                          WT0, WT1, WT2, bcur);

    // Launch 2: edge scatter (first SB blocks) overlapped with gemm L0
    gemm0_scatter_kernel<<<GB + SB, 256, 0, stream>>>(
        x, diff, rec, hid, WT0, b0, bufA, bufB, esrc, edst, bcur, pairs);

    // Launch 3: finalize CSR (needs scatter)
    finalize_kernel<<<NB, 256, 0, stream>>>(bcur, pairs, csr, beg, eend, inv);

    // agg L0: h1 -> B (over r)
    aggregate_kernel<false><<<WB, 256, 0, stream>>>(bufA, bufB, beg, eend, csr, inv,
                                                    nullptr, nullptr, nullptr,
                                                    nullptr, nullptr);

    // L1: h in B; z in-place -> B, r -> A; agg: h2 -> A
    gemm_kernel<128, false><<<GB, 256, 0, stream>>>(bufB, nullptr, nullptr, nullptr, nullptr,
                                                    WT1, b1, bufB, bufA);
    aggregate_kernel<false><<<WB, 256, 0, stream>>>(bufB, bufA, beg, eend, csr, inv,
                                                    nullptr, nullptr, nullptr,
                                                    nullptr, nullptr);

    // L2: h in A; z in-place -> A, r -> B; agg(LAST): fused proj3 -> z3, r3
    gemm_kernel<128, false><<<GB, 256, 0, stream>>>(bufA, nullptr, nullptr, nullptr, nullptr,
                                                    WT2, b2, bufA, bufB);
    aggregate_kernel<true><<<WB, 256, 0, stream>>>(bufA, bufB, beg, eend, csr, inv,
                                                   Wl3, Wr3, b3, z3, r3);

    // final: aggregate scalars, sigmoid + mean
    final_kernel<<<WB, 256, 0, stream>>>(z3, r3, beg, eend, csr, inv, out, partial);
    mean_kernel<<<1, 256, 0, stream>>>(partial, WB, out);
}